// Round 1
// baseline (356.431 us; speedup 1.0000x reference)
//
#include <hip/hip_runtime.h>
#include <hip/hip_bf16.h>
#include <stdint.h>

// ---- problem constants ----
#define BBATCH 4
#define NSEQ   256
#define DIN    64
#define DOUT   128
#define NBASIS 8
#define KTOT   576   // 64 base (silu) + 64*8 spline features
#define KC     32
#define NSTEP  18    // 576/32

typedef __attribute__((ext_vector_type(8))) __bf16 bf16x8;
typedef __attribute__((ext_vector_type(4))) float  f32x4;

__device__ __forceinline__ float wave_sum(float v){
#pragma unroll
  for (int m = 1; m < 64; m <<= 1) v += __shfl_xor(v, m, 64);
  return v;
}

__device__ __forceinline__ float fast_tanh(float y){
  y = fminf(10.f, fmaxf(-10.f, y));
  float e = __expf(2.f * y);
  return (e - 1.f) / (e + 1.f);
}

__device__ __forceinline__ float silu_f(float x){
  return __fdividef(x, 1.f + __expf(-x));
}

__device__ __forceinline__ unsigned short f2bf(float f){
  union { float f; unsigned u; } v; v.f = f;
  unsigned r = (v.u + 0x7fffu + ((v.u >> 16) & 1u)) >> 16;
  return (unsigned short)r;
}

// uniform cubic B-spline: grid [-1,1] step h=0.4, extended by 3 knots each side.
// x in [-1,1] -> interval i = floor((x+1)/h) in [0,5], local t in [0,1).
// nonzero bases are indices i..i+3 (clamped to <8) with standard weights.
__device__ __forceinline__ void spline_w(float x, int &i, float w[4]){
  float u = (x + 1.f) * 2.5f;
  int ii = (int)floorf(u);
  ii = ii < 0 ? 0 : (ii > 5 ? 5 : ii);
  float t = u - (float)ii;
  float t2 = t * t, t3 = t2 * t;
  float it = 1.f - t;
  w[0] = it * it * it * (1.f/6.f);
  w[1] = (3.f*t3 - 6.f*t2 + 4.f) * (1.f/6.f);
  w[2] = (-3.f*t3 + 3.f*t2 + 3.f*t + 1.f) * (1.f/6.f);
  w[3] = t3 * (1.f/6.f);
  i = ii;
}

// ---------- kernel 1: LN(h) and unit-normalized rows ----------
__global__ void k_prep_rows(const float* __restrict__ h,
                            const float* __restrict__ g_in, const float* __restrict__ b_in,
                            float* __restrict__ h_ln, float* __restrict__ hn){
  int row = blockIdx.x;          // 0..1023  (= b*256+n)
  int d   = threadIdx.x;         // 0..63
  float x = h[row*DIN + d];
  float mean = wave_sum(x) * (1.f/64.f);
  float xm = x - mean;
  float var = wave_sum(xm*xm) * (1.f/64.f);
  float hl = xm * rsqrtf(var + 1e-5f) * g_in[d] + b_in[d];
  h_ln[row*DIN + d] = hl;
  float nrm = sqrtf(wave_sum(hl*hl));
  nrm = fmaxf(nrm, 1e-12f);
  hn[row*DIN + d] = hl / nrm;
}

// ---------- kernel 2: S matrix (bf16, [o][k] o=0..63,k=0..575) + w_mean ----------
__global__ void k_prep_S(const float* __restrict__ ka_bw, const float* __restrict__ ka_sw,
                         const float* __restrict__ ka_c,  const float* __restrict__ W_att,
                         unsigned short* __restrict__ S_t, float* __restrict__ wm){
  int blk = blockIdx.x, t = threadIdx.x;
  if (blk < 64){
    int o = blk;
    for (int k = t; k < KTOT; k += 256){
      float v;
      if (k < 64){
        v = ka_bw[o*64 + k];
      } else {
        int km = k - 64, dd = km >> 3, j = km & 7;
        float c = ka_c[(o*64 + dd)*8 + j];
        c = fminf(5.f, fmaxf(-5.f, c));
        v = c * ka_sw[o*64 + dd];
      }
      S_t[o*KTOT + k] = f2bf(v);
    }
  } else {
    if (t < 64){
      float s = 0.f;
      for (int k = 0; k < 256; ++k) s += W_att[t*256 + k];
      wm[t] = s * (1.f/256.f);
    }
  }
}

// ---------- kernel 3: the big one — scores[b,n,m] ----------
// One workgroup (256 thr = 4 waves) handles one (b, n) and 128 m's.
// M=128 pair-rows, N=64 outputs, K=576 features, MFMA 16x16x32 bf16.
__launch_bounds__(256, 3)
__global__ void k_scores(const float* __restrict__ hn,
                         const float* __restrict__ ln_p_g, const float* __restrict__ ln_p_b,
                         const unsigned short* __restrict__ S_t,
                         const float* __restrict__ wm,
                         float* __restrict__ scores){
  __shared__ float          Xs[128][65];   // tanh(LN(prod)) fp32
  __shared__ unsigned short As[128][40];   // A chunk, 32 k + pad (80B rows: 2-way-free banks)
  __shared__ unsigned short Bs[64][40];    // B chunk (o-major)

  int idx  = blockIdx.x;
  int bb   = idx >> 9;
  int n    = (idx >> 1) & 255;
  int m0   = (idx & 1) * 128;

  int tid  = threadIdx.x;
  int lane = tid & 63, wave = tid >> 6;

  float hnn = hn[(bb*NSEQ + n)*DIN + lane];
  float gd  = ln_p_g[lane], bd = ln_p_b[lane];

  // ---- phase 1: X[m_local][d] ----
  for (int r = wave; r < 128; r += 4){
    int m = m0 + r;
    float p  = hnn * hn[(bb*NSEQ + m)*DIN + lane];
    float mean = wave_sum(p) * (1.f/64.f);
    float pm = p - mean;
    float var = wave_sum(pm*pm) * (1.f/64.f);
    float x = fast_tanh(pm * rsqrtf(var + 1e-5f) * gd + bd);
    Xs[r][lane] = x;
  }

  f32x4 acc[2][4];
#pragma unroll
  for (int a = 0; a < 2; ++a)
#pragma unroll
    for (int c = 0; c < 4; ++c){ f32x4 z = {0.f,0.f,0.f,0.f}; acc[a][c] = z; }

  // ---- phase 2: K loop ----
  for (int s = 0; s < NSTEP; ++s){
    int k0 = s * KC;
    __syncthreads();           // previous tile fully consumed; Xs ready (first iter)

    { // fill B chunk: 64 o x 32 k
      int o = tid & 63, grp = tid >> 6;
      uint4 v = *(const uint4*)(S_t + o*KTOT + k0 + grp*8);
      *(uint4*)&Bs[o][grp*8] = v;
    }
    if (s < 2){ // silu features, d = k
      int m = tid >> 1, kb = (tid & 1) * 16;
#pragma unroll
      for (int e = 0; e < 16; ++e){
        float x = Xs[m][k0 + kb + e];
        As[m][kb + e] = f2bf(silu_f(x));
      }
    } else {    // spline features: 4 dims per chunk, 8 bases each
      int d0 = (k0 - 64) >> 3;
#pragma unroll
      for (int pp = 0; pp < 2; ++pp){
        int p  = tid + pp*256;
        int m  = p >> 2, dd = p & 3;
        float x = Xs[m][d0 + dd];
        int i; float w[4];
        spline_w(x, i, w);
        union { unsigned short s[8]; uint4 v; } pk;
#pragma unroll
        for (int j = 0; j < 8; ++j) pk.s[j] = 0;
#pragma unroll
        for (int k = 0; k < 4; ++k){
          int j = i + k;
          if (j < 8) pk.s[j] = f2bf(w[k]);
        }
        *(uint4*)&As[m][dd*8] = pk.v;
      }
    }
    __syncthreads();

    // MFMA: wave owns 32 rows x 64 cols
    int colr = lane & 15, koff = (lane >> 4) * 8;
    bf16x8 a0 = *(const bf16x8*)&As[wave*32 +      colr][koff];
    bf16x8 a1 = *(const bf16x8*)&As[wave*32 + 16 + colr][koff];
#pragma unroll
    for (int nt = 0; nt < 4; ++nt){
      bf16x8 bfr = *(const bf16x8*)&Bs[nt*16 + colr][koff];
      acc[0][nt] = __builtin_amdgcn_mfma_f32_16x16x32_bf16(a0, bfr, acc[0][nt], 0, 0, 0);
      acc[1][nt] = __builtin_amdgcn_mfma_f32_16x16x32_bf16(a1, bfr, acc[1][nt], 0, 0, 0);
    }
  }

  // ---- epilogue: score[m] = sum_o tanh(out[m][o]) * wm[o] ----
  int colr = lane & 15, grp = lane >> 4;
  float wmv[4];
#pragma unroll
  for (int nt = 0; nt < 4; ++nt) wmv[nt] = wm[nt*16 + colr];

#pragma unroll
  for (int mt = 0; mt < 2; ++mt){
    float sacc[4] = {0.f,0.f,0.f,0.f};
#pragma unroll
    for (int nt = 0; nt < 4; ++nt){
#pragma unroll
      for (int r = 0; r < 4; ++r)
        sacc[r] += fast_tanh(acc[mt][nt][r]) * wmv[nt];
    }
#pragma unroll
    for (int off = 1; off < 16; off <<= 1){
#pragma unroll
      for (int r = 0; r < 4; ++r) sacc[r] += __shfl_xor(sacc[r], off, 64);
    }
    if (colr == 0){
      int base = (bb*NSEQ + n)*NSEQ + m0 + wave*32 + mt*16 + grp*4;
#pragma unroll
      for (int r = 0; r < 4; ++r) scores[base + r] = sacc[r];
    }
  }
}

// ---------- kernel 4: softmax over m + h_att = attn @ h_ln ----------
__global__ void k_softmax_att(const float* __restrict__ scores,
                              const float* __restrict__ h_ln,
                              float* __restrict__ h_att){
  __shared__ float att[256];
  __shared__ float redm[4], reds[4];
  __shared__ float part[4][64];
  int row = blockIdx.x;            // b*256+n
  int tid = threadIdx.x, lane = tid & 63, wave = tid >> 6;

  float sc = scores[row*NSEQ + tid] * 0.125f;   // / (sqrt(64)*TEMP)
  float mx = sc;
#pragma unroll
  for (int off = 1; off < 64; off <<= 1) mx = fmaxf(mx, __shfl_xor(mx, off, 64));
  if (lane == 0) redm[wave] = mx;
  __syncthreads();
  mx = fmaxf(fmaxf(redm[0], redm[1]), fmaxf(redm[2], redm[3]));
  float e = __expf(sc - mx);
  float s = wave_sum(e);
  if (lane == 0) reds[wave] = s;
  __syncthreads();
  float tot = reds[0] + reds[1] + reds[2] + reds[3];
  att[tid] = e / tot;
  __syncthreads();

  int d = tid & 63, q = tid >> 6;
  int hb = row & ~255;             // b*256
  float a2 = 0.f;
  for (int m = q*64; m < q*64 + 64; ++m)
    a2 += att[m] * h_ln[(hb + m)*DIN + d];
  part[q][d] = a2;
  __syncthreads();
  if (tid < 64)
    h_att[row*DIN + tid] = part[0][tid] + part[1][tid] + part[2][tid] + part[3][tid];
}

// ---------- kernel 5: out2 = KAN_p(h_att), out3 = KAN_d(h_ln), BN ----------
__global__ void k_final(const float* __restrict__ h_att, const float* __restrict__ h_ln,
                        const float* __restrict__ kp_bw, const float* __restrict__ kp_sw, const float* __restrict__ kp_c,
                        const float* __restrict__ kd_bw, const float* __restrict__ kd_sw, const float* __restrict__ kd_c,
                        const float* __restrict__ bn_g, const float* __restrict__ bn_b,
                        const float* __restrict__ bn_mean, const float* __restrict__ bn_var,
                        float* __restrict__ out){
  __shared__ float sa_s[64], sh_s[64];
  __shared__ float sa_w[64][4], sh_w[64][4];
  __shared__ int   sa_i[64], sh_i[64];
  int row = blockIdx.x, tid = threadIdx.x;

  if (tid < 64){
    float xa = fast_tanh(h_att[row*DIN + tid]);
    sa_s[tid] = silu_f(xa);
    int i; float w[4];
    spline_w(xa, i, w);
    sa_i[tid] = i;
#pragma unroll
    for (int k = 0; k < 4; ++k) sa_w[tid][k] = w[k];

    float xh = fast_tanh(h_ln[row*DIN + tid]);
    sh_s[tid] = silu_f(xh);
    spline_w(xh, i, w);
    sh_i[tid] = i;
#pragma unroll
    for (int k = 0; k < 4; ++k) sh_w[tid][k] = w[k];
  }
  __syncthreads();

  int o = tid;   // 0..127
  float acc = 0.f;
  for (int d = 0; d < 64; ++d){
    acc += sa_s[d] * kp_bw[o*64 + d];
    {
      float sw = kp_sw[o*64 + d]; int i = sa_i[d]; int base = (o*64 + d)*8;
#pragma unroll
      for (int k = 0; k < 4; ++k){
        int j = i + k;
        if (j < 8){
          float c = kp_c[base + j];
          c = fminf(5.f, fmaxf(-5.f, c));
          acc += sa_w[d][k] * c * sw;
        }
      }
    }
    acc += sh_s[d] * kd_bw[o*64 + d];
    {
      float sw = kd_sw[o*64 + d]; int i = sh_i[d]; int base = (o*64 + d)*8;
#pragma unroll
      for (int k = 0; k < 4; ++k){
        int j = i + k;
        if (j < 8){
          float c = kd_c[base + j];
          c = fminf(5.f, fmaxf(-5.f, c));
          acc += sh_w[d][k] * c * sw;
        }
      }
    }
  }
  float r = (acc - bn_mean[o]) * rsqrtf(bn_var[o] + 1e-5f) * bn_g[o] + bn_b[o];
  out[row*DOUT + o] = r;
}

extern "C" void kernel_launch(void* const* d_in, const int* in_sizes, int n_in,
                              void* d_out, int out_size, void* d_ws, size_t ws_size,
                              hipStream_t stream){
  (void)in_sizes; (void)n_in; (void)out_size; (void)ws_size;
  const float* h       = (const float*)d_in[0];
  const float* ln_in_g = (const float*)d_in[1];
  const float* ln_in_b = (const float*)d_in[2];
  const float* ln_p_g  = (const float*)d_in[3];
  const float* ln_p_b  = (const float*)d_in[4];
  const float* ka_bw   = (const float*)d_in[5];
  const float* ka_sw   = (const float*)d_in[6];
  const float* ka_c    = (const float*)d_in[7];
  const float* W_att   = (const float*)d_in[8];
  const float* kp_bw   = (const float*)d_in[9];
  const float* kp_sw   = (const float*)d_in[10];
  const float* kp_c    = (const float*)d_in[11];
  const float* kd_bw   = (const float*)d_in[12];
  const float* kd_sw   = (const float*)d_in[13];
  const float* kd_c    = (const float*)d_in[14];
  const float* bn_g    = (const float*)d_in[15];
  const float* bn_b    = (const float*)d_in[16];
  const float* bn_mean = (const float*)d_in[17];
  const float* bn_var  = (const float*)d_in[18];
  float* out = (float*)d_out;

  char* ws = (char*)d_ws;
  float*          h_ln   = (float*)(ws + 0);                       // 256 KB
  float*          hn     = (float*)(ws + 262144);                  // 256 KB
  unsigned short* S_t    = (unsigned short*)(ws + 524288);         // 72 KB bf16
  float*          wm     = (float*)(ws + 524288 + 73728);          // 256 B
  float*          scores = (float*)(ws + 524288 + 73728 + 256);    // 1 MB
  float*          h_att  = (float*)(ws + 524288 + 73728 + 256 + 1048576); // 256 KB

  k_prep_rows<<<1024, 64, 0, stream>>>(h, ln_in_g, ln_in_b, h_ln, hn);
  k_prep_S<<<65, 256, 0, stream>>>(ka_bw, ka_sw, ka_c, W_att, S_t, wm);
  k_scores<<<2048, 256, 0, stream>>>(hn, ln_p_g, ln_p_b, S_t, wm, scores);
  k_softmax_att<<<1024, 256, 0, stream>>>(scores, h_ln, h_att);
  k_final<<<1024, 128, 0, stream>>>(h_att, h_ln, kp_bw, kp_sw, kp_c,
                                    kd_bw, kd_sw, kd_c, bn_g, bn_b, bn_mean, bn_var, out);
}

// Round 2
// 210.414 us; speedup vs baseline: 1.6940x; 1.6940x over previous
//
#include <hip/hip_runtime.h>
#include <hip/hip_bf16.h>
#include <stdint.h>

// ---- problem constants ----
#define BBATCH 4
#define NSEQ   256
#define DIN    64
#define DOUT   128
#define NBASIS 8
#define KTOT   576   // 64 base (silu) + 64*8 spline features
#define K2TOT  1152  // two KANs worth of features for the final stage
#define KC     32
#define NSTEP  18    // 576/32

typedef __attribute__((ext_vector_type(8))) __bf16 bf16x8;
typedef __attribute__((ext_vector_type(4))) float  f32x4;

__device__ __forceinline__ float wave_sum(float v){
#pragma unroll
  for (int m = 1; m < 64; m <<= 1) v += __shfl_xor(v, m, 64);
  return v;
}

__device__ __forceinline__ float fast_tanh(float y){
  y = fminf(10.f, fmaxf(-10.f, y));
  float e = __expf(2.f * y);
  return (e - 1.f) / (e + 1.f);
}

__device__ __forceinline__ float silu_f(float x){
  return __fdividef(x, 1.f + __expf(-x));
}

__device__ __forceinline__ unsigned short f2bf(float f){
  union { float f; unsigned u; } v; v.f = f;
  unsigned r = (v.u + 0x7fffu + ((v.u >> 16) & 1u)) >> 16;
  return (unsigned short)r;
}

__device__ __forceinline__ float bf2f(unsigned short s){
  union { unsigned u; float f; } v; v.u = ((unsigned)s) << 16;
  return v.f;
}

// uniform cubic B-spline: grid [-1,1] step h=0.4, extended by 3 knots each side.
__device__ __forceinline__ void spline_w(float x, int &i, float w[4]){
  float u = (x + 1.f) * 2.5f;
  int ii = (int)floorf(u);
  ii = ii < 0 ? 0 : (ii > 5 ? 5 : ii);
  float t = u - (float)ii;
  float t2 = t * t, t3 = t2 * t;
  float it = 1.f - t;
  w[0] = it * it * it * (1.f/6.f);
  w[1] = (3.f*t3 - 6.f*t2 + 4.f) * (1.f/6.f);
  w[2] = (-3.f*t3 + 3.f*t2 + 3.f*t + 1.f) * (1.f/6.f);
  w[3] = t3 * (1.f/6.f);
  i = ii;
}

// ---------- kernel 1: LN(h) and unit-normalized rows ----------
__global__ void k_prep_rows(const float* __restrict__ h,
                            const float* __restrict__ g_in, const float* __restrict__ b_in,
                            float* __restrict__ h_ln, float* __restrict__ hn){
  int row = blockIdx.x;          // 0..1023  (= b*256+n)
  int d   = threadIdx.x;         // 0..63
  float x = h[row*DIN + d];
  float mean = wave_sum(x) * (1.f/64.f);
  float xm = x - mean;
  float var = wave_sum(xm*xm) * (1.f/64.f);
  float hl = xm * rsqrtf(var + 1e-5f) * g_in[d] + b_in[d];
  h_ln[row*DIN + d] = hl;
  float nrm = sqrtf(wave_sum(hl*hl));
  nrm = fmaxf(nrm, 1e-12f);
  hn[row*DIN + d] = hl / nrm;
}

// ---------- kernel 2: S matrix (bf16, [o][k]) + w_mean ----------
__global__ void k_prep_S(const float* __restrict__ ka_bw, const float* __restrict__ ka_sw,
                         const float* __restrict__ ka_c,  const float* __restrict__ W_att,
                         unsigned short* __restrict__ S_t, float* __restrict__ wm){
  int blk = blockIdx.x, t = threadIdx.x;
  if (blk < 64){
    int o = blk;
    for (int k = t; k < KTOT; k += 256){
      float v;
      if (k < 64){
        v = ka_bw[o*64 + k];
      } else {
        int km = k - 64, dd = km >> 3, j = km & 7;
        float c = ka_c[(o*64 + dd)*8 + j];
        c = fminf(5.f, fmaxf(-5.f, c));
        v = c * ka_sw[o*64 + dd];
      }
      S_t[o*KTOT + k] = f2bf(v);
    }
  } else {
    if (t < 64){
      float s = 0.f;
      for (int k = 0; k < 256; ++k) s += W_att[t*256 + k];
      wm[t] = s * (1.f/256.f);
    }
  }
}

// ---------- kernel 2b: S2[k][o] k-major combined weights for the final KANs ----------
// k in [0,576): kp (from h_att features); k in [576,1152): kd (from h_ln features)
__global__ void k_prep_S2(const float* __restrict__ kp_bw, const float* __restrict__ kp_sw,
                          const float* __restrict__ kp_c,
                          const float* __restrict__ kd_bw, const float* __restrict__ kd_sw,
                          const float* __restrict__ kd_c,
                          unsigned short* __restrict__ S2){
  int kk = blockIdx.x;           // 0..1151
  int o  = threadIdx.x;          // 0..127
  const float* bw; const float* sw; const float* cc;
  int k = kk;
  if (kk < KTOT){ bw = kp_bw; sw = kp_sw; cc = kp_c; }
  else          { bw = kd_bw; sw = kd_sw; cc = kd_c; k = kk - KTOT; }
  float v;
  if (k < 64){
    v = bw[o*64 + k];
  } else {
    int km = k - 64, d = km >> 3, j = km & 7;
    float c = cc[(o*64 + d)*8 + j];
    c = fminf(5.f, fmaxf(-5.f, c));
    v = c * sw[o*64 + d];
  }
  S2[kk*DOUT + o] = f2bf(v);
}

// ---------- kernel 3: the big one — scores[b,n,m] ----------
__launch_bounds__(256, 3)
__global__ void k_scores(const float* __restrict__ hn,
                         const float* __restrict__ ln_p_g, const float* __restrict__ ln_p_b,
                         const unsigned short* __restrict__ S_t,
                         const float* __restrict__ wm,
                         float* __restrict__ scores){
  __shared__ float          Xs[128][65];   // tanh(LN(prod)) fp32
  __shared__ unsigned short As[128][40];   // A chunk, 32 k + pad
  __shared__ unsigned short Bs[64][40];    // B chunk (o-major)

  int idx  = blockIdx.x;
  int bb   = idx >> 9;
  int n    = (idx >> 1) & 255;
  int m0   = (idx & 1) * 128;

  int tid  = threadIdx.x;
  int lane = tid & 63, wave = tid >> 6;

  float hnn = hn[(bb*NSEQ + n)*DIN + lane];
  float gd  = ln_p_g[lane], bd = ln_p_b[lane];

  // ---- phase 1: X[m_local][d] ----
  for (int r = wave; r < 128; r += 4){
    int m = m0 + r;
    float p  = hnn * hn[(bb*NSEQ + m)*DIN + lane];
    float mean = wave_sum(p) * (1.f/64.f);
    float pm = p - mean;
    float var = wave_sum(pm*pm) * (1.f/64.f);
    float x = fast_tanh(pm * rsqrtf(var + 1e-5f) * gd + bd);
    Xs[r][lane] = x;
  }

  f32x4 acc[2][4];
#pragma unroll
  for (int a = 0; a < 2; ++a)
#pragma unroll
    for (int c = 0; c < 4; ++c){ f32x4 z = {0.f,0.f,0.f,0.f}; acc[a][c] = z; }

  // ---- phase 2: K loop ----
  for (int s = 0; s < NSTEP; ++s){
    int k0 = s * KC;
    __syncthreads();

    { // fill B chunk: 64 o x 32 k
      int o = tid & 63, grp = tid >> 6;
      uint4 v = *(const uint4*)(S_t + o*KTOT + k0 + grp*8);
      *(uint4*)&Bs[o][grp*8] = v;
    }
    if (s < 2){ // silu features, d = k
      int m = tid >> 1, kb = (tid & 1) * 16;
#pragma unroll
      for (int e = 0; e < 16; ++e){
        float x = Xs[m][k0 + kb + e];
        As[m][kb + e] = f2bf(silu_f(x));
      }
    } else {    // spline features: 4 dims per chunk, 8 bases each
      int d0 = (k0 - 64) >> 3;
#pragma unroll
      for (int pp = 0; pp < 2; ++pp){
        int p  = tid + pp*256;
        int m  = p >> 2, dd = p & 3;
        float x = Xs[m][d0 + dd];
        int i; float w[4];
        spline_w(x, i, w);
        union { unsigned short s[8]; uint4 v; } pk;
#pragma unroll
        for (int j = 0; j < 8; ++j) pk.s[j] = 0;
#pragma unroll
        for (int k = 0; k < 4; ++k){
          int j = i + k;
          if (j < 8) pk.s[j] = f2bf(w[k]);
        }
        *(uint4*)&As[m][dd*8] = pk.v;
      }
    }
    __syncthreads();

    int colr = lane & 15, koff = (lane >> 4) * 8;
    bf16x8 a0 = *(const bf16x8*)&As[wave*32 +      colr][koff];
    bf16x8 a1 = *(const bf16x8*)&As[wave*32 + 16 + colr][koff];
#pragma unroll
    for (int nt = 0; nt < 4; ++nt){
      bf16x8 bfr = *(const bf16x8*)&Bs[nt*16 + colr][koff];
      acc[0][nt] = __builtin_amdgcn_mfma_f32_16x16x32_bf16(a0, bfr, acc[0][nt], 0, 0, 0);
      acc[1][nt] = __builtin_amdgcn_mfma_f32_16x16x32_bf16(a1, bfr, acc[1][nt], 0, 0, 0);
    }
  }

  // ---- epilogue: score[m] = sum_o tanh(out[m][o]) * wm[o] ----
  int colr = lane & 15, grp = lane >> 4;
  float wmv[4];
#pragma unroll
  for (int nt = 0; nt < 4; ++nt) wmv[nt] = wm[nt*16 + colr];

#pragma unroll
  for (int mt = 0; mt < 2; ++mt){
    float sacc[4] = {0.f,0.f,0.f,0.f};
#pragma unroll
    for (int nt = 0; nt < 4; ++nt){
#pragma unroll
      for (int r = 0; r < 4; ++r)
        sacc[r] += fast_tanh(acc[mt][nt][r]) * wmv[nt];
    }
#pragma unroll
    for (int off = 1; off < 16; off <<= 1){
#pragma unroll
      for (int r = 0; r < 4; ++r) sacc[r] += __shfl_xor(sacc[r], off, 64);
    }
    if (colr == 0){
      int base = (bb*NSEQ + n)*NSEQ + m0 + wave*32 + mt*16 + grp*4;
#pragma unroll
      for (int r = 0; r < 4; ++r) scores[base + r] = sacc[r];
    }
  }
}

// ---------- kernel 4: softmax over m + h_att = attn @ h_ln ----------
__global__ void k_softmax_att(const float* __restrict__ scores,
                              const float* __restrict__ h_ln,
                              float* __restrict__ h_att){
  __shared__ float att[256];
  __shared__ float redm[4], reds[4];
  __shared__ float part[4][64];
  int row = blockIdx.x;            // b*256+n
  int tid = threadIdx.x, lane = tid & 63, wave = tid >> 6;

  float sc = scores[row*NSEQ + tid] * 0.125f;
  float mx = sc;
#pragma unroll
  for (int off = 1; off < 64; off <<= 1) mx = fmaxf(mx, __shfl_xor(mx, off, 64));
  if (lane == 0) redm[wave] = mx;
  __syncthreads();
  mx = fmaxf(fmaxf(redm[0], redm[1]), fmaxf(redm[2], redm[3]));
  float e = __expf(sc - mx);
  float s = wave_sum(e);
  if (lane == 0) reds[wave] = s;
  __syncthreads();
  float tot = reds[0] + reds[1] + reds[2] + reds[3];
  att[tid] = e / tot;
  __syncthreads();

  int d = tid & 63, q = tid >> 6;
  int hb = row & ~255;             // b*256
  float a2 = 0.f;
  for (int m = q*64; m < q*64 + 64; ++m)
    a2 += att[m] * h_ln[(hb + m)*DIN + d];
  part[q][d] = a2;
  __syncthreads();
  if (tid < 64)
    h_att[row*DIN + tid] = part[0][tid] + part[1][tid] + part[2][tid] + part[3][tid];
}

// ---------- kernel 5: out = BN( feat(row) . S2 ) ----------
// One block per row (1024 blocks, 256 threads). feat[1152] in LDS;
// thread (o = t&127, half = t>>7) sums over 576 k with coalesced bf16 loads.
__launch_bounds__(256, 8)
__global__ void k_final2(const float* __restrict__ h_att, const float* __restrict__ h_ln,
                         const unsigned short* __restrict__ S2,
                         const float* __restrict__ bn_g, const float* __restrict__ bn_b,
                         const float* __restrict__ bn_mean, const float* __restrict__ bn_var,
                         float* __restrict__ out){
  __shared__ float feat[K2TOT];
  __shared__ float part[DOUT];
  int row = blockIdx.x, tid = threadIdx.x;

  if (tid < 128){
    int src = tid >> 6, d = tid & 63;
    float x = src ? h_ln[row*DIN + d] : h_att[row*DIN + d];
    x = fast_tanh(x);
    int base = src * KTOT;
    feat[base + d] = silu_f(x);
    int fb = base + 64 + d*8;
#pragma unroll
    for (int j = 0; j < 8; ++j) feat[fb + j] = 0.f;
    int i; float w[4];
    spline_w(x, i, w);
#pragma unroll
    for (int k = 0; k < 4; ++k){
      int j = i + k;
      if (j < 8) feat[fb + j] = w[k];
    }
  }
  __syncthreads();

  int o = tid & 127, half = tid >> 7;
  const unsigned short* sp = S2 + half*KTOT*DOUT + o;
  const float* fp = feat + half*KTOT;
  float acc = 0.f;
#pragma unroll 8
  for (int k = 0; k < KTOT; ++k)
    acc += fp[k] * bf2f(sp[k*DOUT]);

  if (half) part[o] = acc;
  __syncthreads();
  if (tid < 128){
    float a = acc + part[tid];
    float r = (a - bn_mean[tid]) * rsqrtf(bn_var[tid] + 1e-5f) * bn_g[tid] + bn_b[tid];
    out[row*DOUT + tid] = r;
  }
}

extern "C" void kernel_launch(void* const* d_in, const int* in_sizes, int n_in,
                              void* d_out, int out_size, void* d_ws, size_t ws_size,
                              hipStream_t stream){
  (void)in_sizes; (void)n_in; (void)out_size; (void)ws_size;
  const float* h       = (const float*)d_in[0];
  const float* ln_in_g = (const float*)d_in[1];
  const float* ln_in_b = (const float*)d_in[2];
  const float* ln_p_g  = (const float*)d_in[3];
  const float* ln_p_b  = (const float*)d_in[4];
  const float* ka_bw   = (const float*)d_in[5];
  const float* ka_sw   = (const float*)d_in[6];
  const float* ka_c    = (const float*)d_in[7];
  const float* W_att   = (const float*)d_in[8];
  const float* kp_bw   = (const float*)d_in[9];
  const float* kp_sw   = (const float*)d_in[10];
  const float* kp_c    = (const float*)d_in[11];
  const float* kd_bw   = (const float*)d_in[12];
  const float* kd_sw   = (const float*)d_in[13];
  const float* kd_c    = (const float*)d_in[14];
  const float* bn_g    = (const float*)d_in[15];
  const float* bn_b    = (const float*)d_in[16];
  const float* bn_mean = (const float*)d_in[17];
  const float* bn_var  = (const float*)d_in[18];
  float* out = (float*)d_out;

  char* ws = (char*)d_ws;
  float*          h_ln   = (float*)(ws + 0);                        // 256 KB
  float*          hn     = (float*)(ws + 262144);                   // 256 KB
  unsigned short* S_t    = (unsigned short*)(ws + 524288);          // 72 KB
  float*          wm     = (float*)(ws + 597 * 1024 + 1024 - 1024); // see below
  // explicit offsets:
  wm = (float*)(ws + 598016);                                       // 256 B
  float*          scores = (float*)(ws + 598272);                   // 1 MB
  float*          h_att  = (float*)(ws + 1646848);                  // 256 KB
  unsigned short* S2     = (unsigned short*)(ws + 1908992);         // 288 KB

  k_prep_rows<<<1024, 64, 0, stream>>>(h, ln_in_g, ln_in_b, h_ln, hn);
  k_prep_S<<<65, 256, 0, stream>>>(ka_bw, ka_sw, ka_c, W_att, S_t, wm);
  k_prep_S2<<<K2TOT, 128, 0, stream>>>(kp_bw, kp_sw, kp_c, kd_bw, kd_sw, kd_c, S2);
  k_scores<<<2048, 256, 0, stream>>>(hn, ln_p_g, ln_p_b, S_t, wm, scores);
  k_softmax_att<<<1024, 256, 0, stream>>>(scores, h_ln, h_att);
  k_final2<<<1024, 256, 0, stream>>>(h_att, h_ln, S2, bn_g, bn_b, bn_mean, bn_var, out);
}

// Round 3
// 157.352 us; speedup vs baseline: 2.2652x; 1.3372x over previous
//
#include <hip/hip_runtime.h>
#include <hip/hip_bf16.h>
#include <stdint.h>

// ---- problem constants ----
#define BBATCH 4
#define NSEQ   256
#define DIN    64
#define DOUT   128
#define NBASIS 8
#define KTOT   576   // 64 base (silu) + 64*8 spline features
#define K2TOT  1152  // two KANs worth of features for the final stage
#define NSTEP  18    // 576/32
#define BSTRIDE 584  // padded LDS row stride (bf16) for B: 292 words -> conflict-free b128
#define XSTRIDE 68   // padded LDS row stride (f32) for X: 4m+d bank pattern, conflict-free

typedef __attribute__((ext_vector_type(8))) __bf16 bf16x8;
typedef __attribute__((ext_vector_type(4))) float  f32x4;

__device__ __forceinline__ float wave_sum(float v){
#pragma unroll
  for (int m = 1; m < 64; m <<= 1) v += __shfl_xor(v, m, 64);
  return v;
}

__device__ __forceinline__ float fast_tanh(float y){
  y = fminf(10.f, fmaxf(-10.f, y));
  float e = __expf(2.f * y);
  return (e - 1.f) / (e + 1.f);
}

__device__ __forceinline__ float silu_f(float x){
  return __fdividef(x, 1.f + __expf(-x));
}

__device__ __forceinline__ unsigned short f2bf(float f){
  union { float f; unsigned u; } v; v.f = f;
  unsigned r = (v.u + 0x7fffu + ((v.u >> 16) & 1u)) >> 16;
  return (unsigned short)r;
}

__device__ __forceinline__ float bf2f(unsigned short s){
  union { unsigned u; float f; } v; v.u = ((unsigned)s) << 16;
  return v.f;
}

// pack two f32 -> one u32 of 2 bf16 (round-half-up) in 3 ops via v_perm_b32
__device__ __forceinline__ unsigned pk2(float a, float b){
  union { float f; unsigned u; } ua, ub; ua.f = a; ub.f = b;
  return __builtin_amdgcn_perm(ub.u + 0x8000u, ua.u + 0x8000u, 0x07060302);
}

// uniform cubic B-spline: grid [-1,1] step h=0.4, extended by 3 knots each side.
__device__ __forceinline__ void spline_w(float x, int &i, float w[4]){
  float u = (x + 1.f) * 2.5f;
  int ii = (int)floorf(u);
  ii = ii < 0 ? 0 : (ii > 5 ? 5 : ii);
  float t = u - (float)ii;
  float t2 = t * t, t3 = t2 * t;
  float it = 1.f - t;
  w[0] = it * it * it * (1.f/6.f);
  w[1] = (3.f*t3 - 6.f*t2 + 4.f) * (1.f/6.f);
  w[2] = (-3.f*t3 + 3.f*t2 + 3.f*t + 1.f) * (1.f/6.f);
  w[3] = t3 * (1.f/6.f);
  i = ii;
}

// full 8-slot packed spline basis row (bf16x8) for one x, in-register.
// weights w0..w3 land at slots i..i+3; slot 8 (i=5,k=3) falls off the shift: dropped,
// matching the reference's 8-basis truncation.
__device__ __forceinline__ bf16x8 spline_pack(float x){
  float u = (x + 1.f) * 2.5f;
  int ii = (int)floorf(u);
  ii = ii < 0 ? 0 : (ii > 5 ? 5 : ii);
  float t = u - (float)ii;
  float t2 = t * t, t3 = t2 * t;
  float it = 1.f - t;
  float w0 = it * it * it * (1.f/6.f);
  float w1 = (3.f*t3 - 6.f*t2 + 4.f) * (1.f/6.f);
  float w2 = (-3.f*t3 + 3.f*t2 + 3.f*t + 1.f) * (1.f/6.f);
  float w3 = t3 * (1.f/6.f);
  unsigned long long W = ((unsigned long long)pk2(w2, w3) << 32) | (unsigned long long)pk2(w0, w1);
  int s16 = ii << 4;
  unsigned long long shl_lo = W << (s16 & 63);
  unsigned long long shr    = W >> ((64 - s16) & 63);
  unsigned long long shl_hi = W << ((s16 - 64) & 63);
  bool ge4 = ii >= 4;
  unsigned long long lo = ge4 ? 0ull : shl_lo;
  unsigned long long hi = ge4 ? shl_hi : (ii == 0 ? 0ull : shr);
  union { unsigned long long q[2]; bf16x8 v8; } r;
  r.q[0] = lo; r.q[1] = hi;
  return r.v8;
}

__device__ __forceinline__ bf16x8 silu_pack(const float* xp){
  float4 x0 = *(const float4*)(xp);
  float4 x1 = *(const float4*)(xp + 4);
  union { unsigned u[4]; bf16x8 v8; } r;
  r.u[0] = pk2(silu_f(x0.x), silu_f(x0.y));
  r.u[1] = pk2(silu_f(x0.z), silu_f(x0.w));
  r.u[2] = pk2(silu_f(x1.x), silu_f(x1.y));
  r.u[3] = pk2(silu_f(x1.z), silu_f(x1.w));
  return r.v8;
}

// ---------- kernel 1: LN(h) and unit-normalized rows ----------
__global__ void k_prep_rows(const float* __restrict__ h,
                            const float* __restrict__ g_in, const float* __restrict__ b_in,
                            float* __restrict__ h_ln, float* __restrict__ hn){
  int row = blockIdx.x;          // 0..1023  (= b*256+n)
  int d   = threadIdx.x;         // 0..63
  float x = h[row*DIN + d];
  float mean = wave_sum(x) * (1.f/64.f);
  float xm = x - mean;
  float var = wave_sum(xm*xm) * (1.f/64.f);
  float hl = xm * rsqrtf(var + 1e-5f) * g_in[d] + b_in[d];
  h_ln[row*DIN + d] = hl;
  float nrm = sqrtf(wave_sum(hl*hl));
  nrm = fmaxf(nrm, 1e-12f);
  hn[row*DIN + d] = hl / nrm;
}

// ---------- kernel 2: S matrix (bf16, [o][k]) + w_mean ----------
__global__ void k_prep_S(const float* __restrict__ ka_bw, const float* __restrict__ ka_sw,
                         const float* __restrict__ ka_c,  const float* __restrict__ W_att,
                         unsigned short* __restrict__ S_t, float* __restrict__ wm){
  int blk = blockIdx.x, t = threadIdx.x;
  if (blk < 64){
    int o = blk;
    for (int k = t; k < KTOT; k += 256){
      float v;
      if (k < 64){
        v = ka_bw[o*64 + k];
      } else {
        int km = k - 64, dd = km >> 3, j = km & 7;
        float c = ka_c[(o*64 + dd)*8 + j];
        c = fminf(5.f, fmaxf(-5.f, c));
        v = c * ka_sw[o*64 + dd];
      }
      S_t[o*KTOT + k] = f2bf(v);
    }
  } else {
    if (t < 64){
      float s = 0.f;
      for (int k = 0; k < 256; ++k) s += W_att[t*256 + k];
      wm[t] = s * (1.f/256.f);
    }
  }
}

// ---------- kernel 2b: S2[k][o] k-major combined weights for the final KANs ----------
__global__ void k_prep_S2(const float* __restrict__ kp_bw, const float* __restrict__ kp_sw,
                          const float* __restrict__ kp_c,
                          const float* __restrict__ kd_bw, const float* __restrict__ kd_sw,
                          const float* __restrict__ kd_c,
                          unsigned short* __restrict__ S2){
  int kk = blockIdx.x;           // 0..1151
  int o  = threadIdx.x;          // 0..127
  const float* bw; const float* sw; const float* cc;
  int k = kk;
  if (kk < KTOT){ bw = kp_bw; sw = kp_sw; cc = kp_c; }
  else          { bw = kd_bw; sw = kd_sw; cc = kd_c; k = kk - KTOT; }
  float v;
  if (k < 64){
    v = bw[o*64 + k];
  } else {
    int km = k - 64, d = km >> 3, j = km & 7;
    float c = cc[(o*64 + d)*8 + j];
    c = fminf(5.f, fmaxf(-5.f, c));
    v = c * sw[o*64 + d];
  }
  S2[kk*DOUT + o] = f2bf(v);
}

// ---------- kernel 3: scores[b,n,m] — barrier-free per-wave GEMM ----------
// One block (512 thr = 8 waves) per (b,n). Wave w owns m-rows w*32..w*32+31.
// B (576x64 bf16) staged once in LDS; X (256x64 f32) staged once; A-fragments
// generated fully in-register (spline funnel-shift placement). One barrier total.
__launch_bounds__(512, 2)
__global__ void k_scores(const float* __restrict__ hn,
                         const float* __restrict__ ln_p_g, const float* __restrict__ ln_p_b,
                         const unsigned short* __restrict__ S_t,
                         const float* __restrict__ wm,
                         float* __restrict__ scores){
  __shared__ float          Xs[NSEQ][XSTRIDE];     // 256*68*4 = 69632 B
  __shared__ unsigned short Bs[64][BSTRIDE];       // 64*584*2 = 74752 B   (tot 141 KB)

  int idx  = blockIdx.x;
  int bb   = idx >> 8;
  int n    = idx & 255;

  int tid  = threadIdx.x;
  int lane = tid & 63, wave = tid >> 6;   // 8 waves
  int m0   = wave * 32;

  // ---- stage B: S_t[64][576] -> Bs (each of 512 threads copies 9 x uint4) ----
  {
    int o = tid & 63, h8 = tid >> 6;
    const unsigned short* src = S_t + o * KTOT;
    unsigned short* dst = &Bs[o][0];
#pragma unroll
    for (int i = 0; i < 9; ++i){
      int off = (h8 + i * 8) * 8;        // bf16 offset, 72 uint4 per row
      *(uint4*)(dst + off) = *(const uint4*)(src + off);
    }
  }

  // ---- phase 1: X for this wave's 32 rows (wave-private) ----
  float hnn = hn[(bb*NSEQ + n)*DIN + lane];
  float gd  = ln_p_g[lane], bd = ln_p_b[lane];
#pragma unroll 4
  for (int r = 0; r < 32; ++r){
    int m = m0 + r;
    float p = hnn * hn[(bb*NSEQ + m)*DIN + lane];
    float s1 = p, s2 = p * p;
#pragma unroll
    for (int off = 1; off < 64; off <<= 1){
      s1 += __shfl_xor(s1, off, 64);
      s2 += __shfl_xor(s2, off, 64);
    }
    float mean = s1 * (1.f/64.f);
    float var  = fmaxf(s2 * (1.f/64.f) - mean*mean, 0.f);
    float x = fast_tanh((p - mean) * rsqrtf(var + 1e-5f) * gd + bd);
    Xs[m][lane] = x;
  }
  __syncthreads();   // B staged + (own X already consistent within wave)

  int colr = lane & 15, grp = lane >> 4;
  int mA = m0 + colr, mB = m0 + 16 + colr;

  f32x4 acc[2][4];
#pragma unroll
  for (int a = 0; a < 2; ++a)
#pragma unroll
    for (int c = 0; c < 4; ++c){ f32x4 z = {0.f,0.f,0.f,0.f}; acc[a][c] = z; }

  // ---- silu steps (k = 0..63): lane's 8 k-slots = 8 dims ----
#pragma unroll
  for (int s = 0; s < 2; ++s){
    int kw = s*32 + grp*8;
    bf16x8 a0 = silu_pack(&Xs[mA][kw]);
    bf16x8 a1 = silu_pack(&Xs[mB][kw]);
#pragma unroll
    for (int nt = 0; nt < 4; ++nt){
      bf16x8 bfr = *(const bf16x8*)&Bs[nt*16 + colr][kw];
      acc[0][nt] = __builtin_amdgcn_mfma_f32_16x16x32_bf16(a0, bfr, acc[0][nt], 0, 0, 0);
      acc[1][nt] = __builtin_amdgcn_mfma_f32_16x16x32_bf16(a1, bfr, acc[1][nt], 0, 0, 0);
    }
  }

  // ---- spline steps (k = 64..575): lane's 8 k-slots = one dim's 8 bases ----
  for (int s = 2; s < NSTEP; ++s){
    int d = (s - 2) * 4 + grp;
    bf16x8 a0 = spline_pack(Xs[mA][d]);
    bf16x8 a1 = spline_pack(Xs[mB][d]);
    int kw = s*32 + grp*8;
#pragma unroll
    for (int nt = 0; nt < 4; ++nt){
      bf16x8 bfr = *(const bf16x8*)&Bs[nt*16 + colr][kw];
      acc[0][nt] = __builtin_amdgcn_mfma_f32_16x16x32_bf16(a0, bfr, acc[0][nt], 0, 0, 0);
      acc[1][nt] = __builtin_amdgcn_mfma_f32_16x16x32_bf16(a1, bfr, acc[1][nt], 0, 0, 0);
    }
  }

  // ---- epilogue: score[m] = sum_o tanh(out[m][o]) * wm[o] ----
  float wmv[4];
#pragma unroll
  for (int nt = 0; nt < 4; ++nt) wmv[nt] = wm[nt*16 + colr];

#pragma unroll
  for (int a = 0; a < 2; ++a){
    float sacc[4] = {0.f,0.f,0.f,0.f};
#pragma unroll
    for (int nt = 0; nt < 4; ++nt){
#pragma unroll
      for (int r = 0; r < 4; ++r)
        sacc[r] += fast_tanh(acc[a][nt][r]) * wmv[nt];
    }
#pragma unroll
    for (int off = 1; off < 16; off <<= 1){
#pragma unroll
      for (int r = 0; r < 4; ++r) sacc[r] += __shfl_xor(sacc[r], off, 64);
    }
    if (colr == 0){
      int base = (bb*NSEQ + n)*NSEQ + m0 + a*16 + grp*4;
      float4 v = { sacc[0], sacc[1], sacc[2], sacc[3] };
      *(float4*)&scores[base] = v;
    }
  }
}

// ---------- kernel 4: softmax over m + h_att = attn @ h_ln ----------
__global__ void k_softmax_att(const float* __restrict__ scores,
                              const float* __restrict__ h_ln,
                              float* __restrict__ h_att){
  __shared__ float att[256];
  __shared__ float redm[4], reds[4];
  __shared__ float part[4][64];
  int row = blockIdx.x;            // b*256+n
  int tid = threadIdx.x, lane = tid & 63, wave = tid >> 6;

  float sc = scores[row*NSEQ + tid] * 0.125f;
  float mx = sc;
#pragma unroll
  for (int off = 1; off < 64; off <<= 1) mx = fmaxf(mx, __shfl_xor(mx, off, 64));
  if (lane == 0) redm[wave] = mx;
  __syncthreads();
  mx = fmaxf(fmaxf(redm[0], redm[1]), fmaxf(redm[2], redm[3]));
  float e = __expf(sc - mx);
  float s = wave_sum(e);
  if (lane == 0) reds[wave] = s;
  __syncthreads();
  float tot = reds[0] + reds[1] + reds[2] + reds[3];
  att[tid] = e / tot;
  __syncthreads();

  int d = tid & 63, q = tid >> 6;
  int hb = row & ~255;             // b*256
  float a2 = 0.f;
  for (int m = q*64; m < q*64 + 64; ++m)
    a2 += att[m] * h_ln[(hb + m)*DIN + d];
  part[q][d] = a2;
  __syncthreads();
  if (tid < 64)
    h_att[row*DIN + tid] = part[0][tid] + part[1][tid] + part[2][tid] + part[3][tid];
}

// ---------- kernel 5: out = BN( feat(row) . S2 ) ----------
__launch_bounds__(256, 8)
__global__ void k_final2(const float* __restrict__ h_att, const float* __restrict__ h_ln,
                         const unsigned short* __restrict__ S2,
                         const float* __restrict__ bn_g, const float* __restrict__ bn_b,
                         const float* __restrict__ bn_mean, const float* __restrict__ bn_var,
                         float* __restrict__ out){
  __shared__ float feat[K2TOT];
  __shared__ float part[DOUT];
  int row = blockIdx.x, tid = threadIdx.x;

  if (tid < 128){
    int src = tid >> 6, d = tid & 63;
    float x = src ? h_ln[row*DIN + d] : h_att[row*DIN + d];
    x = fast_tanh(x);
    int base = src * KTOT;
    feat[base + d] = silu_f(x);
    int fb = base + 64 + d*8;
#pragma unroll
    for (int j = 0; j < 8; ++j) feat[fb + j] = 0.f;
    int i; float w[4];
    spline_w(x, i, w);
#pragma unroll
    for (int k = 0; k < 4; ++k){
      int j = i + k;
      if (j < 8) feat[fb + j] = w[k];
    }
  }
  __syncthreads();

  int o = tid & 127, half = tid >> 7;
  const unsigned short* sp = S2 + half*KTOT*DOUT + o;
  const float* fp = feat + half*KTOT;
  float acc = 0.f;
#pragma unroll 8
  for (int k = 0; k < KTOT; ++k)
    acc += fp[k] * bf2f(sp[k*DOUT]);

  if (half) part[o] = acc;
  __syncthreads();
  if (tid < 128){
    float a = acc + part[tid];
    float r = (a - bn_mean[tid]) * rsqrtf(bn_var[tid] + 1e-5f) * bn_g[tid] + bn_b[tid];
    out[row*DOUT + tid] = r;
  }
}

extern "C" void kernel_launch(void* const* d_in, const int* in_sizes, int n_in,
                              void* d_out, int out_size, void* d_ws, size_t ws_size,
                              hipStream_t stream){
  (void)in_sizes; (void)n_in; (void)out_size; (void)ws_size;
  const float* h       = (const float*)d_in[0];
  const float* ln_in_g = (const float*)d_in[1];
  const float* ln_in_b = (const float*)d_in[2];
  const float* ln_p_g  = (const float*)d_in[3];
  const float* ln_p_b  = (const float*)d_in[4];
  const float* ka_bw   = (const float*)d_in[5];
  const float* ka_sw   = (const float*)d_in[6];
  const float* ka_c    = (const float*)d_in[7];
  const float* W_att   = (const float*)d_in[8];
  const float* kp_bw   = (const float*)d_in[9];
  const float* kp_sw   = (const float*)d_in[10];
  const float* kp_c    = (const float*)d_in[11];
  const float* kd_bw   = (const float*)d_in[12];
  const float* kd_sw   = (const float*)d_in[13];
  const float* kd_c    = (const float*)d_in[14];
  const float* bn_g    = (const float*)d_in[15];
  const float* bn_b    = (const float*)d_in[16];
  const float* bn_mean = (const float*)d_in[17];
  const float* bn_var  = (const float*)d_in[18];
  float* out = (float*)d_out;

  char* ws = (char*)d_ws;
  float*          h_ln   = (float*)(ws + 0);                        // 256 KB
  float*          hn     = (float*)(ws + 262144);                   // 256 KB
  unsigned short* S_t    = (unsigned short*)(ws + 524288);          // 72 KB
  float*          wm     = (float*)(ws + 598016);                   // 256 B
  float*          scores = (float*)(ws + 598272);                   // 1 MB
  float*          h_att  = (float*)(ws + 1646848);                  // 256 KB
  unsigned short* S2     = (unsigned short*)(ws + 1908992);         // 288 KB

  k_prep_rows<<<1024, 64, 0, stream>>>(h, ln_in_g, ln_in_b, h_ln, hn);
  k_prep_S<<<65, 256, 0, stream>>>(ka_bw, ka_sw, ka_c, W_att, S_t, wm);
  k_prep_S2<<<K2TOT, 128, 0, stream>>>(kp_bw, kp_sw, kp_c, kd_bw, kd_sw, kd_c, S2);
  k_scores<<<1024, 512, 0, stream>>>(hn, ln_p_g, ln_p_b, S_t, wm, scores);
  k_softmax_att<<<1024, 256, 0, stream>>>(scores, h_ln, h_att);
  k_final2<<<1024, 256, 0, stream>>>(h_att, h_ln, S2, bn_g, bn_b, bn_mean, bn_var, out);
}

// Round 4
// 133.068 us; speedup vs baseline: 2.6786x; 1.1825x over previous
//
#include <hip/hip_runtime.h>
#include <hip/hip_bf16.h>
#include <stdint.h>

// ---- problem constants ----
#define BBATCH 4
#define NSEQ   256
#define DIN    64
#define DOUT   128
#define NBASIS 8
#define KTOT   576   // 64 base (silu) + 64*8 spline features
#define K2TOT  1152  // two KANs worth of features for the final stage
#define NSTEP  18    // 576/32
#define XSTRIDE 67   // ODD word stride: per-thread strided f32 reads are 2-way (free)

typedef __attribute__((ext_vector_type(8))) __bf16 bf16x8;
typedef __attribute__((ext_vector_type(4))) float  f32x4;

__device__ __forceinline__ float wave_sum(float v){
#pragma unroll
  for (int m = 1; m < 64; m <<= 1) v += __shfl_xor(v, m, 64);
  return v;
}

__device__ __forceinline__ float fast_tanh(float y){
  y = fminf(10.f, fmaxf(-10.f, y));
  float e = __expf(2.f * y);
  return (e - 1.f) / (e + 1.f);
}

__device__ __forceinline__ float silu_f(float x){
  return __fdividef(x, 1.f + __expf(-x));
}

__device__ __forceinline__ unsigned short f2bf(float f){
  union { float f; unsigned u; } v; v.f = f;
  unsigned r = (v.u + 0x7fffu + ((v.u >> 16) & 1u)) >> 16;
  return (unsigned short)r;
}

__device__ __forceinline__ float bf2f(unsigned short s){
  union { unsigned u; float f; } v; v.u = ((unsigned)s) << 16;
  return v.f;
}

// pack two f32 -> one u32 of 2 bf16 (round-half-up) in 3 ops via v_perm_b32
__device__ __forceinline__ unsigned pk2(float a, float b){
  union { float f; unsigned u; } ua, ub; ua.f = a; ub.f = b;
  return __builtin_amdgcn_perm(ub.u + 0x8000u, ua.u + 0x8000u, 0x07060302);
}

// uniform cubic B-spline: grid [-1,1] step h=0.4, extended by 3 knots each side.
__device__ __forceinline__ void spline_w(float x, int &i, float w[4]){
  float u = (x + 1.f) * 2.5f;
  int ii = (int)floorf(u);
  ii = ii < 0 ? 0 : (ii > 5 ? 5 : ii);
  float t = u - (float)ii;
  float t2 = t * t, t3 = t2 * t;
  float it = 1.f - t;
  w[0] = it * it * it * (1.f/6.f);
  w[1] = (3.f*t3 - 6.f*t2 + 4.f) * (1.f/6.f);
  w[2] = (-3.f*t3 + 3.f*t2 + 3.f*t + 1.f) * (1.f/6.f);
  w[3] = t3 * (1.f/6.f);
  i = ii;
}

// full 8-slot packed spline basis row (bf16x8) for one x, in-register.
// weights w0..w3 land at slots i..i+3; slot 8 (i=5,k=3) falls off the shift:
// dropped, matching the reference's 8-basis truncation.
__device__ __forceinline__ bf16x8 spline_pack(float x){
  float u = (x + 1.f) * 2.5f;
  int ii = (int)floorf(u);
  ii = ii < 0 ? 0 : (ii > 5 ? 5 : ii);
  float t = u - (float)ii;
  float t2 = t * t, t3 = t2 * t;
  float it = 1.f - t;
  float w0 = it * it * it * (1.f/6.f);
  float w1 = (3.f*t3 - 6.f*t2 + 4.f) * (1.f/6.f);
  float w2 = (-3.f*t3 + 3.f*t2 + 3.f*t + 1.f) * (1.f/6.f);
  float w3 = t3 * (1.f/6.f);
  unsigned long long W = ((unsigned long long)pk2(w2, w3) << 32) | (unsigned long long)pk2(w0, w1);
  int s16 = ii << 4;
  unsigned long long shl_lo = W << (s16 & 63);
  unsigned long long shr    = W >> ((64 - s16) & 63);
  unsigned long long shl_hi = W << ((s16 - 64) & 63);
  bool ge4 = ii >= 4;
  unsigned long long lo = ge4 ? 0ull : shl_lo;
  unsigned long long hi = ge4 ? shl_hi : (ii == 0 ? 0ull : shr);
  union { unsigned long long q[2]; bf16x8 v8; } r;
  r.q[0] = lo; r.q[1] = hi;
  return r.v8;
}

// silu of 8 consecutive f32 (scalar LDS reads; stride-67 rows are not 16B aligned)
__device__ __forceinline__ bf16x8 silu_pack_s(const float* xp){
  union { unsigned u[4]; bf16x8 v8; } r;
#pragma unroll
  for (int e = 0; e < 4; ++e)
    r.u[e] = pk2(silu_f(xp[2*e]), silu_f(xp[2*e+1]));
  return r.v8;
}

// ---------- kernel 1: LN(h) and unit-normalized rows ----------
__global__ void k_prep_rows(const float* __restrict__ h,
                            const float* __restrict__ g_in, const float* __restrict__ b_in,
                            float* __restrict__ h_ln, float* __restrict__ hn){
  int row = blockIdx.x;          // 0..1023  (= b*256+n)
  int d   = threadIdx.x;         // 0..63
  float x = h[row*DIN + d];
  float mean = wave_sum(x) * (1.f/64.f);
  float xm = x - mean;
  float var = wave_sum(xm*xm) * (1.f/64.f);
  float hl = xm * rsqrtf(var + 1e-5f) * g_in[d] + b_in[d];
  h_ln[row*DIN + d] = hl;
  float nrm = sqrtf(wave_sum(hl*hl));
  nrm = fmaxf(nrm, 1e-12f);
  hn[row*DIN + d] = hl / nrm;
}

// ---------- kernel 2: S matrix (bf16, [o][k]) + w_mean ----------
__global__ void k_prep_S(const float* __restrict__ ka_bw, const float* __restrict__ ka_sw,
                         const float* __restrict__ ka_c,  const float* __restrict__ W_att,
                         unsigned short* __restrict__ S_t, float* __restrict__ wm){
  int blk = blockIdx.x, t = threadIdx.x;
  if (blk < 64){
    int o = blk;
    for (int k = t; k < KTOT; k += 256){
      float v;
      if (k < 64){
        v = ka_bw[o*64 + k];
      } else {
        int km = k - 64, dd = km >> 3, j = km & 7;
        float c = ka_c[(o*64 + dd)*8 + j];
        c = fminf(5.f, fmaxf(-5.f, c));
        v = c * ka_sw[o*64 + dd];
      }
      S_t[o*KTOT + k] = f2bf(v);
    }
  } else {
    if (t < 64){
      float s = 0.f;
      for (int k = 0; k < 256; ++k) s += W_att[t*256 + k];
      wm[t] = s * (1.f/256.f);
    }
  }
}

// ---------- kernel 2b: S2[k][o] k-major combined weights for the final KANs ----------
__global__ void k_prep_S2(const float* __restrict__ kp_bw, const float* __restrict__ kp_sw,
                          const float* __restrict__ kp_c,
                          const float* __restrict__ kd_bw, const float* __restrict__ kd_sw,
                          const float* __restrict__ kd_c,
                          unsigned short* __restrict__ S2){
  int kk = blockIdx.x;           // 0..1151
  int o  = threadIdx.x;          // 0..127
  const float* bw; const float* sw; const float* cc;
  int k = kk;
  if (kk < KTOT){ bw = kp_bw; sw = kp_sw; cc = kp_c; }
  else          { bw = kd_bw; sw = kd_sw; cc = kd_c; k = kk - KTOT; }
  float v;
  if (k < 64){
    v = bw[o*64 + k];
  } else {
    int km = k - 64, d = km >> 3, j = km & 7;
    float c = cc[(o*64 + d)*8 + j];
    c = fminf(5.f, fmaxf(-5.f, c));
    v = c * sw[o*64 + d];
  }
  S2[kk*DOUT + o] = f2bf(v);
}

// ---------- kernel 3: scores[b,n,m] ----------
// One block (512 thr = 8 waves) per (b,n). Wave w owns m-rows w*32..w*32+31
// (staged by itself, LN'd by its own threads, consumed by its own MFMAs).
// B fragments read straight from global (L1/L2-hot, prefetched per step).
// LDS = 69.4 KB -> 2 blocks/CU (4 waves/SIMD).
__launch_bounds__(512, 4)
__global__ void k_scores(const float* __restrict__ hn,
                         const float* __restrict__ ln_p_g, const float* __restrict__ ln_p_b,
                         const unsigned short* __restrict__ S_t,
                         const float* __restrict__ wm,
                         float* __restrict__ scores){
  __shared__ float Xs[NSEQ * XSTRIDE];   // [256][67] f32 = 68608 B
  __shared__ float hnn_l[64], g_l[64], b_l[64];

  int idx  = blockIdx.x;
  int bb   = idx >> 8;
  int n    = idx & 255;

  int tid  = threadIdx.x;
  int lane = tid & 63, wave = tid >> 6;   // 8 waves
  int m0   = wave * 32;

  // ---- phase 0: each wave stages its own 32 hn rows (8 KB, coalesced) ----
  {
    const float* src = hn + (bb*NSEQ + m0)*DIN;
#pragma unroll
    for (int j = 0; j < 8; ++j){
      int f4 = j*64 + lane;                 // float4 index in this wave's 2048 floats
      float4 v = *(const float4*)(src + f4*4);
      int r = f4 >> 4, c = (f4 & 15) * 4;
      float* dst = &Xs[(m0 + r)*XSTRIDE + c];
      dst[0] = v.x; dst[1] = v.y; dst[2] = v.z; dst[3] = v.w;
    }
    if (tid < 64)        g_l[tid]        = ln_p_g[tid];
    else if (tid < 128)  hnn_l[tid-64]   = hn[(bb*NSEQ + n)*DIN + tid - 64];
    else if (tid < 192)  b_l[tid-128]    = ln_p_b[tid-128];
  }
  __syncthreads();

  // ---- phase 1: per-thread LN + tanh, in place ----
  {
    int r = tid >> 1, h = tid & 1;
    float* row = &Xs[r*XSTRIDE + h*32];
    const float* hp = &hnn_l[h*32];
    float s1 = 0.f, s2 = 0.f;
#pragma unroll
    for (int i = 0; i < 32; ++i){
      float p = hp[i] * row[i];
      s1 += p; s2 = fmaf(p, p, s2);
    }
    s1 += __shfl_xor(s1, 1, 64);
    s2 += __shfl_xor(s2, 1, 64);
    float mean = s1 * (1.f/64.f);
    float var  = fmaxf(s2 * (1.f/64.f) - mean*mean, 0.f);
    float inv  = rsqrtf(var + 1e-5f);
    const float* gp = &g_l[h*32];
    const float* bp = &b_l[h*32];
#pragma unroll
    for (int i = 0; i < 32; ++i){
      float p = hp[i] * row[i];
      row[i] = fast_tanh((p - mean) * inv * gp[i] + bp[i]);
    }
  }
  __syncthreads();

  // ---- phase 2: MFMA K-loop, B from global ----
  int colr = lane & 15, grp = lane >> 4;
  const float* rowA = &Xs[(m0 + colr)*XSTRIDE];
  const float* rowB = &Xs[(m0 + 16 + colr)*XSTRIDE];
  const unsigned short* bp0 = S_t + colr*KTOT;

  f32x4 acc[2][4];
#pragma unroll
  for (int a = 0; a < 2; ++a)
#pragma unroll
    for (int c = 0; c < 4; ++c){ f32x4 z = {0.f,0.f,0.f,0.f}; acc[a][c] = z; }

  // silu steps (k = 0..63): lane's 8 k-slots = 8 dims
#pragma unroll
  for (int s = 0; s < 2; ++s){
    int kw = s*32 + grp*8;
    bf16x8 bf[4];
#pragma unroll
    for (int nt = 0; nt < 4; ++nt)
      bf[nt] = *(const bf16x8*)(bp0 + nt*16*KTOT + kw);
    bf16x8 a0 = silu_pack_s(rowA + kw);
    bf16x8 a1 = silu_pack_s(rowB + kw);
#pragma unroll
    for (int nt = 0; nt < 4; ++nt){
      acc[0][nt] = __builtin_amdgcn_mfma_f32_16x16x32_bf16(a0, bf[nt], acc[0][nt], 0, 0, 0);
      acc[1][nt] = __builtin_amdgcn_mfma_f32_16x16x32_bf16(a1, bf[nt], acc[1][nt], 0, 0, 0);
    }
  }

  // spline steps (k = 64..575): lane's 8 k-slots = one dim's 8 bases
#pragma unroll 4
  for (int s = 2; s < NSTEP; ++s){
    int kw = s*32 + grp*8;
    int d  = (s - 2)*4 + grp;
    bf16x8 bf[4];
#pragma unroll
    for (int nt = 0; nt < 4; ++nt)
      bf[nt] = *(const bf16x8*)(bp0 + nt*16*KTOT + kw);
    bf16x8 a0 = spline_pack(rowA[d]);
    bf16x8 a1 = spline_pack(rowB[d]);
#pragma unroll
    for (int nt = 0; nt < 4; ++nt){
      acc[0][nt] = __builtin_amdgcn_mfma_f32_16x16x32_bf16(a0, bf[nt], acc[0][nt], 0, 0, 0);
      acc[1][nt] = __builtin_amdgcn_mfma_f32_16x16x32_bf16(a1, bf[nt], acc[1][nt], 0, 0, 0);
    }
  }

  // ---- epilogue: score[m] = sum_o tanh(out[m][o]) * wm[o] ----
  float wmv[4];
#pragma unroll
  for (int nt = 0; nt < 4; ++nt) wmv[nt] = wm[nt*16 + colr];

#pragma unroll
  for (int a = 0; a < 2; ++a){
    float sacc[4] = {0.f,0.f,0.f,0.f};
#pragma unroll
    for (int nt = 0; nt < 4; ++nt){
#pragma unroll
      for (int r = 0; r < 4; ++r)
        sacc[r] += fast_tanh(acc[a][nt][r]) * wmv[nt];
    }
#pragma unroll
    for (int off = 1; off < 16; off <<= 1){
#pragma unroll
      for (int r = 0; r < 4; ++r) sacc[r] += __shfl_xor(sacc[r], off, 64);
    }
    if (colr == 0){
      int base = (bb*NSEQ + n)*NSEQ + m0 + a*16 + grp*4;
      float4 v = { sacc[0], sacc[1], sacc[2], sacc[3] };
      *(float4*)&scores[base] = v;
    }
  }
}

// ---------- kernel 4: softmax over m + h_att = attn @ h_ln ----------
__global__ void k_softmax_att(const float* __restrict__ scores,
                              const float* __restrict__ h_ln,
                              float* __restrict__ h_att){
  __shared__ float att[256];
  __shared__ float redm[4], reds[4];
  __shared__ float part[4][64];
  int row = blockIdx.x;            // b*256+n
  int tid = threadIdx.x, lane = tid & 63, wave = tid >> 6;

  float sc = scores[row*NSEQ + tid] * 0.125f;
  float mx = sc;
#pragma unroll
  for (int off = 1; off < 64; off <<= 1) mx = fmaxf(mx, __shfl_xor(mx, off, 64));
  if (lane == 0) redm[wave] = mx;
  __syncthreads();
  mx = fmaxf(fmaxf(redm[0], redm[1]), fmaxf(redm[2], redm[3]));
  float e = __expf(sc - mx);
  float s = wave_sum(e);
  if (lane == 0) reds[wave] = s;
  __syncthreads();
  float tot = reds[0] + reds[1] + reds[2] + reds[3];
  att[tid] = e / tot;
  __syncthreads();

  int d = tid & 63, q = tid >> 6;
  int hb = row & ~255;             // b*256
  float a2 = 0.f;
  for (int m = q*64; m < q*64 + 64; ++m)
    a2 += att[m] * h_ln[(hb + m)*DIN + d];
  part[q][d] = a2;
  __syncthreads();
  if (tid < 64)
    h_att[row*DIN + tid] = part[0][tid] + part[1][tid] + part[2][tid] + part[3][tid];
}

// ---------- kernel 5: out = BN( feat(row) . S2 ) ----------
__launch_bounds__(256, 8)
__global__ void k_final2(const float* __restrict__ h_att, const float* __restrict__ h_ln,
                         const unsigned short* __restrict__ S2,
                         const float* __restrict__ bn_g, const float* __restrict__ bn_b,
                         const float* __restrict__ bn_mean, const float* __restrict__ bn_var,
                         float* __restrict__ out){
  __shared__ float feat[K2TOT];
  __shared__ float part[DOUT];
  int row = blockIdx.x, tid = threadIdx.x;

  if (tid < 128){
    int src = tid >> 6, d = tid & 63;
    float x = src ? h_ln[row*DIN + d] : h_att[row*DIN + d];
    x = fast_tanh(x);
    int base = src * KTOT;
    feat[base + d] = silu_f(x);
    int fb = base + 64 + d*8;
#pragma unroll
    for (int j = 0; j < 8; ++j) feat[fb + j] = 0.f;
    int i; float w[4];
    spline_w(x, i, w);
#pragma unroll
    for (int k = 0; k < 4; ++k){
      int j = i + k;
      if (j < 8) feat[fb + j] = w[k];
    }
  }
  __syncthreads();

  int o = tid & 127, half = tid >> 7;
  const unsigned short* sp = S2 + half*KTOT*DOUT + o;
  const float* fp = feat + half*KTOT;
  float acc = 0.f;
#pragma unroll 8
  for (int k = 0; k < KTOT; ++k)
    acc += fp[k] * bf2f(sp[k*DOUT]);

  if (half) part[o] = acc;
  __syncthreads();
  if (tid < 128){
    float a = acc + part[tid];
    float r = (a - bn_mean[tid]) * rsqrtf(bn_var[tid] + 1e-5f) * bn_g[tid] + bn_b[tid];
    out[row*DOUT + tid] = r;
  }
}

extern "C" void kernel_launch(void* const* d_in, const int* in_sizes, int n_in,
                              void* d_out, int out_size, void* d_ws, size_t ws_size,
                              hipStream_t stream){
  (void)in_sizes; (void)n_in; (void)out_size; (void)ws_size;
  const float* h       = (const float*)d_in[0];
  const float* ln_in_g = (const float*)d_in[1];
  const float* ln_in_b = (const float*)d_in[2];
  const float* ln_p_g  = (const float*)d_in[3];
  const float* ln_p_b  = (const float*)d_in[4];
  const float* ka_bw   = (const float*)d_in[5];
  const float* ka_sw   = (const float*)d_in[6];
  const float* ka_c    = (const float*)d_in[7];
  const float* W_att   = (const float*)d_in[8];
  const float* kp_bw   = (const float*)d_in[9];
  const float* kp_sw   = (const float*)d_in[10];
  const float* kp_c    = (const float*)d_in[11];
  const float* kd_bw   = (const float*)d_in[12];
  const float* kd_sw   = (const float*)d_in[13];
  const float* kd_c    = (const float*)d_in[14];
  const float* bn_g    = (const float*)d_in[15];
  const float* bn_b    = (const float*)d_in[16];
  const float* bn_mean = (const float*)d_in[17];
  const float* bn_var  = (const float*)d_in[18];
  float* out = (float*)d_out;

  char* ws = (char*)d_ws;
  float*          h_ln   = (float*)(ws + 0);                        // 256 KB
  float*          hn     = (float*)(ws + 262144);                   // 256 KB
  unsigned short* S_t    = (unsigned short*)(ws + 524288);          // 72 KB
  float*          wm     = (float*)(ws + 598016);                   // 256 B
  float*          scores = (float*)(ws + 598272);                   // 1 MB
  float*          h_att  = (float*)(ws + 1646848);                  // 256 KB
  unsigned short* S2     = (unsigned short*)(ws + 1908992);         // 288 KB

  k_prep_rows<<<1024, 64, 0, stream>>>(h, ln_in_g, ln_in_b, h_ln, hn);
  k_prep_S<<<65, 256, 0, stream>>>(ka_bw, ka_sw, ka_c, W_att, S_t, wm);
  k_prep_S2<<<K2TOT, 128, 0, stream>>>(kp_bw, kp_sw, kp_c, kd_bw, kd_sw, kd_c, S2);
  k_scores<<<1024, 512, 0, stream>>>(hn, ln_p_g, ln_p_b, S_t, wm, scores);
  k_softmax_att<<<1024, 256, 0, stream>>>(scores, h_ln, h_att);
  k_final2<<<1024, 256, 0, stream>>>(h_att, h_ln, S2, bn_g, bn_b, bn_mean, bn_var, out);
}

// Round 5
// 115.652 us; speedup vs baseline: 3.0819x; 1.1506x over previous
//
#include <hip/hip_runtime.h>
#include <hip/hip_bf16.h>
#include <stdint.h>

// ---- problem constants ----
#define BBATCH 4
#define NSEQ   256
#define DIN    64
#define DOUT   128
#define NBASIS 8
#define KTOT   576   // 64 base (silu) + 64*8 spline features
#define K2TOT  1152  // two KANs worth of features for the final stage
#define NSTEP  18    // 576/32
#define XSTRIDE 67   // ODD word stride: per-thread strided f32 reads are 2-way (free)

typedef __attribute__((ext_vector_type(8))) __bf16 bf16x8;
typedef __attribute__((ext_vector_type(4))) float  f32x4;

__device__ __forceinline__ float wave_sum(float v){
#pragma unroll
  for (int m = 1; m < 64; m <<= 1) v += __shfl_xor(v, m, 64);
  return v;
}

__device__ __forceinline__ float fast_tanh(float y){
  y = fminf(10.f, fmaxf(-10.f, y));
  float e = __expf(2.f * y);
  return (e - 1.f) / (e + 1.f);
}

__device__ __forceinline__ float silu_f(float x){
  return __fdividef(x, 1.f + __expf(-x));
}

__device__ __forceinline__ unsigned short f2bf(float f){
  union { float f; unsigned u; } v; v.f = f;
  unsigned r = (v.u + 0x7fffu + ((v.u >> 16) & 1u)) >> 16;
  return (unsigned short)r;
}

__device__ __forceinline__ float bf2f(unsigned short s){
  union { unsigned u; float f; } v; v.u = ((unsigned)s) << 16;
  return v.f;
}

__device__ __forceinline__ float bf2f_lo(unsigned w){   // low 16 bits -> f32
  union { unsigned u; float f; } v; v.u = w << 16;
  return v.f;
}
__device__ __forceinline__ float bf2f_hi(unsigned w){   // high 16 bits -> f32
  union { unsigned u; float f; } v; v.u = w & 0xffff0000u;
  return v.f;
}

// pack two f32 -> one u32 of 2 bf16 (round-half-up) in 3 ops via v_perm_b32
__device__ __forceinline__ unsigned pk2(float a, float b){
  union { float f; unsigned u; } ua, ub; ua.f = a; ub.f = b;
  return __builtin_amdgcn_perm(ub.u + 0x8000u, ua.u + 0x8000u, 0x07060302);
}

// uniform cubic B-spline: grid [-1,1] step h=0.4, extended by 3 knots each side.
__device__ __forceinline__ void spline_w(float x, int &i, float w[4]){
  float u = (x + 1.f) * 2.5f;
  int ii = (int)floorf(u);
  ii = ii < 0 ? 0 : (ii > 5 ? 5 : ii);
  float t = u - (float)ii;
  float t2 = t * t, t3 = t2 * t;
  float it = 1.f - t;
  w[0] = it * it * it * (1.f/6.f);
  w[1] = (3.f*t3 - 6.f*t2 + 4.f) * (1.f/6.f);
  w[2] = (-3.f*t3 + 3.f*t2 + 3.f*t + 1.f) * (1.f/6.f);
  w[3] = t3 * (1.f/6.f);
  i = ii;
}

// full 8-slot packed spline basis row (bf16x8) for one x, in-register.
__device__ __forceinline__ bf16x8 spline_pack(float x){
  float u = (x + 1.f) * 2.5f;
  int ii = (int)floorf(u);
  ii = ii < 0 ? 0 : (ii > 5 ? 5 : ii);
  float t = u - (float)ii;
  float t2 = t * t, t3 = t2 * t;
  float it = 1.f - t;
  float w0 = it * it * it * (1.f/6.f);
  float w1 = (3.f*t3 - 6.f*t2 + 4.f) * (1.f/6.f);
  float w2 = (-3.f*t3 + 3.f*t2 + 3.f*t + 1.f) * (1.f/6.f);
  float w3 = t3 * (1.f/6.f);
  unsigned long long W = ((unsigned long long)pk2(w2, w3) << 32) | (unsigned long long)pk2(w0, w1);
  int s16 = ii << 4;
  unsigned long long shl_lo = W << (s16 & 63);
  unsigned long long shr    = W >> ((64 - s16) & 63);
  unsigned long long shl_hi = W << ((s16 - 64) & 63);
  bool ge4 = ii >= 4;
  unsigned long long lo = ge4 ? 0ull : shl_lo;
  unsigned long long hi = ge4 ? shl_hi : (ii == 0 ? 0ull : shr);
  union { unsigned long long q[2]; bf16x8 v8; } r;
  r.q[0] = lo; r.q[1] = hi;
  return r.v8;
}

// silu of 8 consecutive f32 (scalar LDS reads; stride-67 rows are not 16B aligned)
__device__ __forceinline__ bf16x8 silu_pack_s(const float* xp){
  union { unsigned u[4]; bf16x8 v8; } r;
#pragma unroll
  for (int e = 0; e < 4; ++e)
    r.u[e] = pk2(silu_f(xp[2*e]), silu_f(xp[2*e+1]));
  return r.v8;
}

// ---------- kernel 1: LN(h) and unit-normalized rows ----------
__global__ void k_prep_rows(const float* __restrict__ h,
                            const float* __restrict__ g_in, const float* __restrict__ b_in,
                            float* __restrict__ h_ln, float* __restrict__ hn){
  int row = blockIdx.x;          // 0..1023  (= b*256+n)
  int d   = threadIdx.x;         // 0..63
  float x = h[row*DIN + d];
  float mean = wave_sum(x) * (1.f/64.f);
  float xm = x - mean;
  float var = wave_sum(xm*xm) * (1.f/64.f);
  float hl = xm * rsqrtf(var + 1e-5f) * g_in[d] + b_in[d];
  h_ln[row*DIN + d] = hl;
  float nrm = sqrtf(wave_sum(hl*hl));
  nrm = fmaxf(nrm, 1e-12f);
  hn[row*DIN + d] = hl / nrm;
}

// ---------- kernel 2: S matrix (bf16, [o][k]) + w_mean ----------
__global__ void k_prep_S(const float* __restrict__ ka_bw, const float* __restrict__ ka_sw,
                         const float* __restrict__ ka_c,  const float* __restrict__ W_att,
                         unsigned short* __restrict__ S_t, float* __restrict__ wm){
  int blk = blockIdx.x, t = threadIdx.x;
  if (blk < 64){
    int o = blk;
    for (int k = t; k < KTOT; k += 256){
      float v;
      if (k < 64){
        v = ka_bw[o*64 + k];
      } else {
        int km = k - 64, dd = km >> 3, j = km & 7;
        float c = ka_c[(o*64 + dd)*8 + j];
        c = fminf(5.f, fmaxf(-5.f, c));
        v = c * ka_sw[o*64 + dd];
      }
      S_t[o*KTOT + k] = f2bf(v);
    }
  } else {
    if (t < 64){
      float s = 0.f;
      for (int k = 0; k < 256; ++k) s += W_att[t*256 + k];
      wm[t] = s * (1.f/256.f);
    }
  }
}

// ---------- kernel 2b: S2[o][kk] row-major combined weights for the final KANs ----------
// kk in [0,576): kp (h_att features); kk in [576,1152): kd (h_ln features)
__global__ void k_prep_S2(const float* __restrict__ kp_bw, const float* __restrict__ kp_sw,
                          const float* __restrict__ kp_c,
                          const float* __restrict__ kd_bw, const float* __restrict__ kd_sw,
                          const float* __restrict__ kd_c,
                          unsigned short* __restrict__ S2){
  int o = blockIdx.x;            // 0..127
  int t = threadIdx.x;           // 0..255
  for (int kk = t; kk < K2TOT; kk += 256){
    const float* bw; const float* sw; const float* cc;
    int k = kk;
    if (kk < KTOT){ bw = kp_bw; sw = kp_sw; cc = kp_c; }
    else          { bw = kd_bw; sw = kd_sw; cc = kd_c; k = kk - KTOT; }
    float v;
    if (k < 64){
      v = bw[o*64 + k];
    } else {
      int km = k - 64, d = km >> 3, j = km & 7;
      float c = cc[(o*64 + d)*8 + j];
      c = fminf(5.f, fmaxf(-5.f, c));
      v = c * sw[o*64 + d];
    }
    S2[o*K2TOT + kk] = f2bf(v);
  }
}

// ---------- kernel 3: scores[b,n,m] — symmetric-exploiting ----------
// scores[b,n,m] == scores[b,m,n] bitwise (prod symmetric, identical op order).
// Block (b,n): wave w (m-strip [32w,32w+32)) active iff w >= n>>5.
// Active waves write scores[n,m] AND scores[m,n]. Coverage: tile(m)>=tile(n)
// direct; tile(m)<tile(n) via block m's transpose write. Double-writes are
// bitwise identical -> benign.
__launch_bounds__(512, 4)
__global__ void k_scores(const float* __restrict__ hn,
                         const float* __restrict__ ln_p_g, const float* __restrict__ ln_p_b,
                         const unsigned short* __restrict__ S_t,
                         const float* __restrict__ wm,
                         float* __restrict__ scores){
  __shared__ float Xs[NSEQ * XSTRIDE];   // [256][67] f32 = 68608 B
  __shared__ float hnn_l[64], g_l[64], b_l[64];

  int idx  = blockIdx.x;
  int bb   = idx & 3;            // heavy (small n) blocks dispatched first
  int n    = idx >> 2;

  int tid  = threadIdx.x;
  int lane = tid & 63, wave = tid >> 6;   // 8 waves
  int m0   = wave * 32;
  bool active = (wave >= (n >> 5));

  // ---- phase 0 ----
  if (wave == 7){                 // wave 7 always active
    g_l[lane]   = ln_p_g[lane];
    b_l[lane]   = ln_p_b[lane];
    hnn_l[lane] = hn[(bb*NSEQ + n)*DIN + lane];
  }
  if (active){
    const float* src = hn + (bb*NSEQ + m0)*DIN;
#pragma unroll
    for (int j = 0; j < 8; ++j){
      int f4 = j*64 + lane;                 // float4 index in this wave's 2048 floats
      float4 v = *(const float4*)(src + f4*4);
      int r = f4 >> 4, c = (f4 & 15) * 4;
      float* dst = &Xs[(m0 + r)*XSTRIDE + c];
      dst[0] = v.x; dst[1] = v.y; dst[2] = v.z; dst[3] = v.w;
    }
  }
  __syncthreads();

  // ---- phase 1: per-thread LN + tanh, in place (rows are wave-aligned) ----
  if (active){
    int r = tid >> 1, h = tid & 1;
    float* row = &Xs[r*XSTRIDE + h*32];
    const float* hp = &hnn_l[h*32];
    float s1 = 0.f, s2 = 0.f;
#pragma unroll
    for (int i = 0; i < 32; ++i){
      float p = hp[i] * row[i];
      s1 += p; s2 = fmaf(p, p, s2);
    }
    s1 += __shfl_xor(s1, 1, 64);
    s2 += __shfl_xor(s2, 1, 64);
    float mean = s1 * (1.f/64.f);
    float var  = fmaxf(s2 * (1.f/64.f) - mean*mean, 0.f);
    float inv  = rsqrtf(var + 1e-5f);
    const float* gp = &g_l[h*32];
    const float* bp = &b_l[h*32];
#pragma unroll
    for (int i = 0; i < 32; ++i){
      float p = hp[i] * row[i];
      row[i] = fast_tanh((p - mean) * inv * gp[i] + bp[i]);
    }
  }
  __syncthreads();
  if (!active) return;            // no barriers after this point

  // ---- phase 2: MFMA K-loop, B from global ----
  int colr = lane & 15, grp = lane >> 4;
  const float* rowA = &Xs[(m0 + colr)*XSTRIDE];
  const float* rowB = &Xs[(m0 + 16 + colr)*XSTRIDE];
  const unsigned short* bp0 = S_t + colr*KTOT;

  f32x4 acc[2][4];
#pragma unroll
  for (int a = 0; a < 2; ++a)
#pragma unroll
    for (int c = 0; c < 4; ++c){ f32x4 z = {0.f,0.f,0.f,0.f}; acc[a][c] = z; }

  // silu steps (k = 0..63): lane's 8 k-slots = 8 dims
#pragma unroll
  for (int s = 0; s < 2; ++s){
    int kw = s*32 + grp*8;
    bf16x8 bf[4];
#pragma unroll
    for (int nt = 0; nt < 4; ++nt)
      bf[nt] = *(const bf16x8*)(bp0 + nt*16*KTOT + kw);
    bf16x8 a0 = silu_pack_s(rowA + kw);
    bf16x8 a1 = silu_pack_s(rowB + kw);
#pragma unroll
    for (int nt = 0; nt < 4; ++nt){
      acc[0][nt] = __builtin_amdgcn_mfma_f32_16x16x32_bf16(a0, bf[nt], acc[0][nt], 0, 0, 0);
      acc[1][nt] = __builtin_amdgcn_mfma_f32_16x16x32_bf16(a1, bf[nt], acc[1][nt], 0, 0, 0);
    }
  }

  // spline steps (k = 64..575): lane's 8 k-slots = one dim's 8 bases
#pragma unroll 4
  for (int s = 2; s < NSTEP; ++s){
    int kw = s*32 + grp*8;
    int d  = (s - 2)*4 + grp;
    bf16x8 bf[4];
#pragma unroll
    for (int nt = 0; nt < 4; ++nt)
      bf[nt] = *(const bf16x8*)(bp0 + nt*16*KTOT + kw);
    bf16x8 a0 = spline_pack(rowA[d]);
    bf16x8 a1 = spline_pack(rowB[d]);
#pragma unroll
    for (int nt = 0; nt < 4; ++nt){
      acc[0][nt] = __builtin_amdgcn_mfma_f32_16x16x32_bf16(a0, bf[nt], acc[0][nt], 0, 0, 0);
      acc[1][nt] = __builtin_amdgcn_mfma_f32_16x16x32_bf16(a1, bf[nt], acc[1][nt], 0, 0, 0);
    }
  }

  // ---- epilogue: score[m] = sum_o tanh(out[m][o]) * wm[o]; write direct + transpose ----
  float wmv[4];
#pragma unroll
  for (int nt = 0; nt < 4; ++nt) wmv[nt] = wm[nt*16 + colr];

#pragma unroll
  for (int a = 0; a < 2; ++a){
    float sacc[4] = {0.f,0.f,0.f,0.f};
#pragma unroll
    for (int nt = 0; nt < 4; ++nt){
#pragma unroll
      for (int r = 0; r < 4; ++r)
        sacc[r] += fast_tanh(acc[a][nt][r]) * wmv[nt];
    }
#pragma unroll
    for (int off = 1; off < 16; off <<= 1){
#pragma unroll
      for (int r = 0; r < 4; ++r) sacc[r] += __shfl_xor(sacc[r], off, 64);
    }
    if (colr == 0){
      int mb   = m0 + a*16 + grp*4;
      int base = (bb*NSEQ + n)*NSEQ + mb;
      float4 v = { sacc[0], sacc[1], sacc[2], sacc[3] };
      *(float4*)&scores[base] = v;
      // transpose entries scores[m, n]
      int tb = bb*NSEQ*NSEQ + n;
#pragma unroll
      for (int r = 0; r < 4; ++r)
        scores[tb + (mb + r)*NSEQ] = sacc[r];
    }
  }
}

// ---------- kernel 4: softmax over m + h_att = attn @ h_ln ----------
__global__ void k_softmax_att(const float* __restrict__ scores,
                              const float* __restrict__ h_ln,
                              float* __restrict__ h_att){
  __shared__ float att[256];
  __shared__ float redm[4], reds[4];
  __shared__ float part[4][64];
  int row = blockIdx.x;            // b*256+n
  int tid = threadIdx.x, lane = tid & 63, wave = tid >> 6;

  float sc = scores[row*NSEQ + tid] * 0.125f;
  float mx = sc;
#pragma unroll
  for (int off = 1; off < 64; off <<= 1) mx = fmaxf(mx, __shfl_xor(mx, off, 64));
  if (lane == 0) redm[wave] = mx;
  __syncthreads();
  mx = fmaxf(fmaxf(redm[0], redm[1]), fmaxf(redm[2], redm[3]));
  float e = __expf(sc - mx);
  float s = wave_sum(e);
  if (lane == 0) reds[wave] = s;
  __syncthreads();
  float tot = reds[0] + reds[1] + reds[2] + reds[3];
  att[tid] = e / tot;
  __syncthreads();

  int d = tid & 63, q = tid >> 6;
  int hb = row & ~255;             // b*256
  float a2 = 0.f;
  for (int m = q*64; m < q*64 + 64; ++m)
    a2 += att[m] * h_ln[(hb + m)*DIN + d];
  part[q][d] = a2;
  __syncthreads();
  if (tid < 64)
    h_att[row*DIN + tid] = part[0][tid] + part[1][tid] + part[2][tid] + part[3][tid];
}

// ---------- kernel 5: out = BN( feat(row) . S2 ) ----------
__launch_bounds__(256, 8)
__global__ void k_final2(const float* __restrict__ h_att, const float* __restrict__ h_ln,
                         const unsigned short* __restrict__ S2,
                         const float* __restrict__ bn_g, const float* __restrict__ bn_b,
                         const float* __restrict__ bn_mean, const float* __restrict__ bn_var,
                         float* __restrict__ out){
  __shared__ float feat[K2TOT];
  __shared__ float part[DOUT];
  int row = blockIdx.x, tid = threadIdx.x;

  if (tid < 128){
    int src = tid >> 6, d = tid & 63;
    float x = src ? h_ln[row*DIN + d] : h_att[row*DIN + d];
    x = fast_tanh(x);
    int base = src * KTOT;
    feat[base + d] = silu_f(x);
    int fb = base + 64 + d*8;
#pragma unroll
    for (int j = 0; j < 8; ++j) feat[fb + j] = 0.f;
    int i; float w[4];
    spline_w(x, i, w);
#pragma unroll
    for (int k = 0; k < 4; ++k){
      int j = i + k;
      if (j < 8) feat[fb + j] = w[k];
    }
  }
  __syncthreads();

  int o = tid & 127, half = tid >> 7;
  const unsigned short* sp = S2 + o*K2TOT + half*KTOT;
  const float* fp = feat + half*KTOT;
  float acc = 0.f;
#pragma unroll 4
  for (int j = 0; j < KTOT/8; ++j){
    uint4  w  = *(const uint4*)(sp + j*8);
    float4 f0 = *(const float4*)(fp + j*8);
    float4 f1 = *(const float4*)(fp + j*8 + 4);
    acc = fmaf(f0.x, bf2f_lo(w.x), acc);
    acc = fmaf(f0.y, bf2f_hi(w.x), acc);
    acc = fmaf(f0.z, bf2f_lo(w.y), acc);
    acc = fmaf(f0.w, bf2f_hi(w.y), acc);
    acc = fmaf(f1.x, bf2f_lo(w.z), acc);
    acc = fmaf(f1.y, bf2f_hi(w.z), acc);
    acc = fmaf(f1.z, bf2f_lo(w.w), acc);
    acc = fmaf(f1.w, bf2f_hi(w.w), acc);
  }

  if (half) part[o] = acc;
  __syncthreads();
  if (tid < 128){
    float a = acc + part[tid];
    float r = (a - bn_mean[tid]) * rsqrtf(bn_var[tid] + 1e-5f) * bn_g[tid] + bn_b[tid];
    out[row*DOUT + tid] = r;
  }
}

extern "C" void kernel_launch(void* const* d_in, const int* in_sizes, int n_in,
                              void* d_out, int out_size, void* d_ws, size_t ws_size,
                              hipStream_t stream){
  (void)in_sizes; (void)n_in; (void)out_size; (void)ws_size;
  const float* h       = (const float*)d_in[0];
  const float* ln_in_g = (const float*)d_in[1];
  const float* ln_in_b = (const float*)d_in[2];
  const float* ln_p_g  = (const float*)d_in[3];
  const float* ln_p_b  = (const float*)d_in[4];
  const float* ka_bw   = (const float*)d_in[5];
  const float* ka_sw   = (const float*)d_in[6];
  const float* ka_c    = (const float*)d_in[7];
  const float* W_att   = (const float*)d_in[8];
  const float* kp_bw   = (const float*)d_in[9];
  const float* kp_sw   = (const float*)d_in[10];
  const float* kp_c    = (const float*)d_in[11];
  const float* kd_bw   = (const float*)d_in[12];
  const float* kd_sw   = (const float*)d_in[13];
  const float* kd_c    = (const float*)d_in[14];
  const float* bn_g    = (const float*)d_in[15];
  const float* bn_b    = (const float*)d_in[16];
  const float* bn_mean = (const float*)d_in[17];
  const float* bn_var  = (const float*)d_in[18];
  float* out = (float*)d_out;

  char* ws = (char*)d_ws;
  float*          h_ln   = (float*)(ws + 0);                        // 256 KB
  float*          hn     = (float*)(ws + 262144);                   // 256 KB
  unsigned short* S_t    = (unsigned short*)(ws + 524288);          // 72 KB
  float*          wm     = (float*)(ws + 598016);                   // 256 B
  float*          scores = (float*)(ws + 598272);                   // 1 MB
  float*          h_att  = (float*)(ws + 1646848);                  // 256 KB
  unsigned short* S2     = (unsigned short*)(ws + 1908992);         // 288 KB

  k_prep_rows<<<1024, 64, 0, stream>>>(h, ln_in_g, ln_in_b, h_ln, hn);
  k_prep_S<<<65, 256, 0, stream>>>(ka_bw, ka_sw, ka_c, W_att, S_t, wm);
  k_prep_S2<<<128, 256, 0, stream>>>(kp_bw, kp_sw, kp_c, kd_bw, kd_sw, kd_c, S2);
  k_scores<<<1024, 512, 0, stream>>>(hn, ln_p_g, ln_p_b, S_t, wm, scores);
  k_softmax_att<<<1024, 256, 0, stream>>>(scores, h_ln, h_att);
  k_final2<<<1024, 256, 0, stream>>>(h_att, h_ln, S2, bn_g, bn_b, bn_mean, bn_var, out);
}